// Round 6
// baseline (416.903 us; speedup 1.0000x reference)
//
#include <hip/hip_runtime.h>

#define HH 256
#define WW 256
#define CC 64
#define FF 128
#define NN 8
#define OUTC 384           // 3*C sep + C lap + F learned
#define HW (HH * WW)

typedef __attribute__((ext_vector_type(8))) short bf16x8;
typedef __attribute__((ext_vector_type(4))) float f32x4;

__device__ __forceinline__ int clampi(int v, int lo, int hi) {
    return v < lo ? lo : (v > hi ? hi : v);
}

// round-to-nearest-even fp32 -> bf16
static __device__ __forceinline__ unsigned short f2bf(float x) {
    unsigned u = __builtin_bit_cast(unsigned, x);
    u += 0x7FFFu + ((u >> 16) & 1u);
    return (unsigned short)(u >> 16);
}
static __device__ __forceinline__ unsigned packbf(float a, float b) {
    return (unsigned)f2bf(a) | ((unsigned)f2bf(b) << 16);
}
static __device__ __forceinline__ void nts(float* p, float a, float b, float c, float d) {
    f32x4 v = {a, b, c, d};
    __builtin_nontemporal_store(v, reinterpret_cast<f32x4*>(p));
}

// ---------------------------------------------------------------------------
// k0: W[f][c][3][3] fp32 -> ws bf16 [tap][f][c]   (9*128*64 elems, 147456 B)
// ---------------------------------------------------------------------------
__global__ __launch_bounds__(256) void wT_kernel(const float* __restrict__ Wl,
                                                 unsigned* __restrict__ wsW) {
    int e = blockIdx.x * 256 + threadIdx.x;     // over 9*128*32 = 36864 pairs
    if (e >= 9 * 128 * 32) return;
    int t = e >> 12;
    int rem = e & 4095;
    int f = rem >> 5;
    int c2 = rem & 31;
    float a = Wl[(size_t)f * 576 + (size_t)(2 * c2) * 9 + t];
    float b = Wl[(size_t)f * 576 + (size_t)(2 * c2 + 1) * 9 + t];
    wsW[t * 4096 + f * 32 + c2] = packbf(a, b);
}

// ---------------------------------------------------------------------------
// k1: pack x NCHW fp32 -> x-tilde NHWC bf16 (64 MB at d_ws+256KB).
// thread = 1 pixel: 64 coalesced scalar reads, 8x uint4 = 128 B contig write.
// ---------------------------------------------------------------------------
__global__ __launch_bounds__(256) void pack_kernel(const float* __restrict__ x,
                                                   unsigned short* __restrict__ xt) {
    int g = blockIdx.x * 256 + threadIdx.x;   // n*HW + px (524288 total)
    int n = g >> 16;
    int px = g & 65535;
    const float* xp = x + (size_t)n * CC * HW + px;
    uint4* o = reinterpret_cast<uint4*>(xt + (size_t)g * 64);
#pragma unroll
    for (int c8 = 0; c8 < 8; ++c8) {
        unsigned u0 = packbf(xp[(size_t)(c8 * 8 + 0) * HW], xp[(size_t)(c8 * 8 + 1) * HW]);
        unsigned u1 = packbf(xp[(size_t)(c8 * 8 + 2) * HW], xp[(size_t)(c8 * 8 + 3) * HW]);
        unsigned u2 = packbf(xp[(size_t)(c8 * 8 + 4) * HW], xp[(size_t)(c8 * 8 + 5) * HW]);
        unsigned u3 = packbf(xp[(size_t)(c8 * 8 + 6) * HW], xp[(size_t)(c8 * 8 + 7) * HW]);
        o[c8] = make_uint4(u0, u1, u2, u3);
    }
}

// ---------------------------------------------------------------------------
// k2: learned conv. Block = 4 waves = 128f x (64w x 2h). No x staging, no
// barriers: b-frags are direct 16B loads from NHWC x-tilde (L1/L2 resident),
// a-frags 16B loads from L2-resident wsW. Per-wave LDS epilogue transpose
// (no cross-wave sharing) -> 256B nt stores.
// ---------------------------------------------------------------------------
__global__ __launch_bounds__(256) void learned_kernel(const unsigned short* __restrict__ wsW,
                                                      const unsigned short* __restrict__ xt,
                                                      const float* __restrict__ bl,
                                                      float* __restrict__ out) {
    __shared__ float lds_e[4][16][68];        // 17408 B, per-wave slabs

    int q = blockIdx.x;                       // n*512 + yb*4 + xb
    int tile = q & 511;
    int n = q >> 9;
    int y0 = (tile >> 2) * 2;                 // 128 bands of 2 rows
    int x0 = (tile & 3) * 64;                 // 4 tiles of 64 cols

    int tid = threadIdx.x;
    int lane = tid & 63;
    int w = tid >> 6;
    int wf = w >> 1;                          // f-half (0..1)
    int wp = w & 1;                           // row (0..1)
    int lr = lane & 15;
    int lk = lane >> 4;

    // precomputed clamped byte offsets into x-tilde
    const char* xtb = reinterpret_cast<const char*>(xt) + (size_t)n * HW * 128;
    int colb[4][3];
#pragma unroll
    for (int j = 0; j < 4; ++j)
#pragma unroll
        for (int dx = 0; dx < 3; ++dx)
            colb[j][dx] = clampi(x0 + j * 16 + lr + dx - 1, 0, WW - 1) * 128;
    int rowb[3];
#pragma unroll
    for (int dy = 0; dy < 3; ++dy)
        rowb[dy] = clampi(y0 + wp + dy - 1, 0, HH - 1) * (WW * 128);

    f32x4 acc[4][4] = {};                     // [mt (16f tile)][j (16px group)]

#pragma unroll
    for (int t = 0; t < 9; ++t) {
        int dy = t / 3, dx = t - 3 * (t / 3);
        bf16x8 a[4][2];
#pragma unroll
        for (int mt = 0; mt < 4; ++mt)
#pragma unroll
            for (int kk = 0; kk < 2; ++kk)
                a[mt][kk] = *reinterpret_cast<const bf16x8*>(
                    wsW + (size_t)t * 8192 + (wf * 64 + mt * 16 + lr) * 64 + kk * 32 + lk * 8);
#pragma unroll
        for (int kk = 0; kk < 2; ++kk) {
            bf16x8 bb[4];
#pragma unroll
            for (int j = 0; j < 4; ++j)
                bb[j] = *reinterpret_cast<const bf16x8*>(
                    xtb + rowb[dy] + colb[j][dx] + kk * 64 + lk * 16);
#pragma unroll
            for (int mt = 0; mt < 4; ++mt)
#pragma unroll
                for (int j = 0; j < 4; ++j)
                    acc[mt][j] = __builtin_amdgcn_mfma_f32_16x16x32_bf16(
                        a[mt][kk], bb[j], acc[mt][j], 0, 0, 0);
        }
    }

    // epilogue: per-wave transpose via private LDS slab; 256B nt stores
    float* le = &lds_e[w][0][0];
#pragma unroll
    for (int mt = 0; mt < 4; ++mt) {
#pragma unroll
        for (int i = 0; i < 4; ++i) {
            int f16 = lk * 4 + i;
            float bv = bl[wf * 64 + mt * 16 + f16];
#pragma unroll
            for (int j = 0; j < 4; ++j)
                le[f16 * 68 + j * 16 + lr] = acc[mt][j][i] + bv;
        }
#pragma unroll
        for (int p = 0; p < 4; ++p) {
            int f16 = p * 4 + lk;
            const float* s = &le[f16 * 68 + lr * 4];
            int f = wf * 64 + mt * 16 + f16;
            nts(out + (size_t)(n * OUTC + 256 + f) * HW + (size_t)(y0 + wp) * WW + x0 + lr * 4,
                s[0], s[1], s[2], s[3]);
        }
    }
}

// ---------------------------------------------------------------------------
// k3: depthwise fixed filters, pure streaming. block = (n, c, 8 rows),
// 512 thr = 8 rows x 64 float4-cols, fp32-exact, nt stores.
// ---------------------------------------------------------------------------
__global__ __launch_bounds__(512) void dw_kernel(const float* __restrict__ x,
                                                 float* __restrict__ out) {
    int b = blockIdx.x;                   // 8n * 64c * 32y8
    int y8 = b & 31;
    int c = (b >> 5) & 63;
    int n = b >> 11;

    int t = threadIdx.x;
    int r = t >> 6;                       // 0..7
    int col = (t & 63) * 4;
    int y = y8 * 8 + r;

    const float* xp = x + ((size_t)(n * CC + c)) * HW;
    int ym = y == 0 ? 0 : y - 1;
    int yp = y == HH - 1 ? HH - 1 : y + 1;
    int cl = col == 0 ? 0 : col - 1;
    int cr = (col + 4 > WW - 1) ? WW - 1 : col + 4;

    float4 top = *(const float4*)(xp + (size_t)ym * WW + col);
    float4 mid = *(const float4*)(xp + (size_t)y  * WW + col);
    float4 bot = *(const float4*)(xp + (size_t)yp * WW + col);
    float tl = xp[(size_t)ym * WW + cl], tr = xp[(size_t)ym * WW + cr];
    float ml = xp[(size_t)y  * WW + cl], mr = xp[(size_t)y  * WW + cr];
    float blv = xp[(size_t)yp * WW + cl], br = xp[(size_t)yp * WW + cr];

    float tv[6] = {tl, top.x, top.y, top.z, top.w, tr};
    float mv[6] = {ml, mid.x, mid.y, mid.z, mid.w, mr};
    float bv[6] = {blv, bot.x, bot.y, bot.z, bot.w, br};

    float o0[4], o1[4], o2[4], o3[4];
#pragma unroll
    for (int j = 0; j < 4; ++j) {
        float tL = tv[j], tC = tv[j + 1], tR = tv[j + 2];
        float mL = mv[j], mC = mv[j + 1], mR = mv[j + 2];
        float bL = bv[j], bC = bv[j + 1], bR = bv[j + 2];
        o0[j] = mC;
        o1[j] = (tL + 2.0f * tC + tR) - (bL + 2.0f * bC + bR);
        o2[j] = (tL - tR) + 2.0f * (mL - mR) + (bL - bR);
        o3[j] = 4.0f * mC - tC - bC - mL - mR;
    }

    float* ob = out + ((size_t)n * OUTC) * HW + (size_t)y * WW + col;
    nts(ob + (size_t)(c * 3 + 0) * HW, o0[0], o0[1], o0[2], o0[3]);
    nts(ob + (size_t)(c * 3 + 1) * HW, o1[0], o1[1], o1[2], o1[3]);
    nts(ob + (size_t)(c * 3 + 2) * HW, o2[0], o2[1], o2[2], o2[3]);
    nts(ob + (size_t)(192 + c)   * HW, o3[0], o3[1], o3[2], o3[3]);
}

extern "C" void kernel_launch(void* const* d_in, const int* in_sizes, int n_in,
                              void* d_out, int out_size, void* d_ws, size_t ws_size,
                              hipStream_t stream) {
    const float* x  = (const float*)d_in[0];
    const float* Wl = (const float*)d_in[1];
    const float* bl = (const float*)d_in[2];
    float* out = (float*)d_out;

    unsigned* wsW = (unsigned*)d_ws;                                        // 147456 B
    unsigned short* xt = (unsigned short*)((char*)d_ws + 262144);           // 64 MB

    wT_kernel<<<144, 256, 0, stream>>>(Wl, wsW);
    pack_kernel<<<2048, 256, 0, stream>>>(x, xt);
    learned_kernel<<<NN * 512, 256, 0, stream>>>((const unsigned short*)wsW, xt, bl, out);
    dw_kernel<<<NN * 64 * 32, 512, 0, stream>>>(x, out);
}

// Round 7
// 289.546 us; speedup vs baseline: 1.4399x; 1.4399x over previous
//
#include <hip/hip_runtime.h>

#define HH 256
#define WW 256
#define CC 64
#define FF 128
#define NN 8
#define OUTC 384           // 3*C sep + C lap + F learned
#define HW (HH * WW)

typedef __attribute__((ext_vector_type(8))) short bf16x8;
typedef __attribute__((ext_vector_type(4))) float f32x4;

__device__ __forceinline__ int clampi(int v, int lo, int hi) {
    return v < lo ? lo : (v > hi ? hi : v);
}

// round-to-nearest-even fp32 -> bf16
static __device__ __forceinline__ unsigned short f2bf(float x) {
    unsigned u = __builtin_bit_cast(unsigned, x);
    u += 0x7FFFu + ((u >> 16) & 1u);
    return (unsigned short)(u >> 16);
}
static __device__ __forceinline__ unsigned packbf(float a, float b) {
    return (unsigned)f2bf(a) | ((unsigned)f2bf(b) << 16);
}
static __device__ __forceinline__ float bf2f(unsigned short s) {
    return __builtin_bit_cast(float, (unsigned)s << 16);
}
static __device__ __forceinline__ void nts(float* p, float a, float b, float c, float d) {
    f32x4 v = {a, b, c, d};
    __builtin_nontemporal_store(v, reinterpret_cast<f32x4*>(p));
}

// ---------------------------------------------------------------------------
// k0: W[f][c][3][3] fp32 -> wsW bf16 [t][kg][f][8ch]  (9*8*128*8 = 147456 B)
// lane-contiguous in f so a-frag loads are 256B segments.
// ---------------------------------------------------------------------------
__global__ __launch_bounds__(256) void wT_kernel(const float* __restrict__ Wl,
                                                 unsigned short* __restrict__ wsW) {
    int e = blockIdx.x * 256 + threadIdx.x;     // (t, kg, f): 9*8*128 = 9216
    if (e >= 9216) return;
    int t = e >> 10;
    int rem = e & 1023;
    int kg = rem >> 7;
    int f = rem & 127;
    unsigned u[4];
#pragma unroll
    for (int j2 = 0; j2 < 4; ++j2) {
        float a = Wl[(size_t)f * 576 + (size_t)(kg * 8 + 2 * j2) * 9 + t];
        float b = Wl[(size_t)f * 576 + (size_t)(kg * 8 + 2 * j2 + 1) * 9 + t];
        u[j2] = packbf(a, b);
    }
    *reinterpret_cast<uint4*>(wsW + (size_t)e * 8) = make_uint4(u[0], u[1], u[2], u[3]);
}

// ---------------------------------------------------------------------------
// k1: pack x NCHW fp32 -> x-tilde NC8HW8 bf16: xt[n][cg][h][w][8ch].
// block = (n, cg, y); thread = w. 8 coalesced plane reads, 1KB/wave write.
// Regular (cached) stores: we WANT x-tilde L3-resident for k2/k3.
// ---------------------------------------------------------------------------
__global__ __launch_bounds__(256) void pack_kernel(const float* __restrict__ x,
                                                   unsigned short* __restrict__ xt) {
    int b = blockIdx.x;                   // n*2048 + cg*256 + y
    int y = b & 255;
    int cg = (b >> 8) & 7;
    int n = b >> 11;
    int w = threadIdx.x;
    const float* xp = x + ((size_t)(n * CC + cg * 8)) * HW + (size_t)y * WW + w;
    unsigned u[4];
#pragma unroll
    for (int j2 = 0; j2 < 4; ++j2)
        u[j2] = packbf(xp[(size_t)(2 * j2) * HW], xp[(size_t)(2 * j2 + 1) * HW]);
    *reinterpret_cast<uint4*>(xt + ((size_t)((n * 8 + cg) * HH + y) * WW + w) * 8) =
        make_uint4(u[0], u[1], u[2], u[3]);
}

// ---------------------------------------------------------------------------
// k2: learned conv, zero staging / zero barriers. Block = 4 waves =
// 128 f x 128 px x 1 row; wave = 64 f x 64 px, acc[4][4].
// b-frags: direct 16B loads from NC8HW8 x-tilde -> 256B segments per quarter-
// wave (L1/L3 resident). a-frags: 256B segments from wsW (L1-resident).
// Epilogue: per-wave LDS transpose, 256B nt stores, no cross-wave barriers.
// ---------------------------------------------------------------------------
__global__ __launch_bounds__(256, 4) void learned_kernel(const unsigned short* __restrict__ wsW,
                                                         const unsigned short* __restrict__ xt,
                                                         const float* __restrict__ bl,
                                                         float* __restrict__ out) {
    __shared__ float lds_e[4][16][68];        // 17408 B, per-wave slabs

    int q = blockIdx.x;                       // n*512 + y*2 + xs
    int xs = q & 1;
    int y = (q >> 1) & 255;
    int n = q >> 9;

    int tid = threadIdx.x;
    int lane = tid & 63;
    int w = tid >> 6;
    int wf = w >> 1;                          // f-half (0..1)
    int ws = w & 1;                           // px 64-segment (0..1)
    int x0 = xs * 128 + ws * 64;
    int lr = lane & 15;
    int lk = lane >> 4;

    const char* xb = reinterpret_cast<const char*>(xt) + (size_t)n * (8 * HH * WW * 16);

    // clamped column byte-offsets (per-lane), and clamped rows (scalar)
    int colb[4][3];
#pragma unroll
    for (int j = 0; j < 4; ++j)
#pragma unroll
        for (int dx = 0; dx < 3; ++dx)
            colb[j][dx] = clampi(x0 + j * 16 + lr + dx - 1, 0, WW - 1) * 16;

    f32x4 acc[4][4] = {};                     // [mt (16f tile)][j (16px group)]

#pragma unroll
    for (int t = 0; t < 9; ++t) {
        int dy = t / 3, dx = t - 3 * (t / 3);
        int yc = clampi(y + dy - 1, 0, HH - 1);
#pragma unroll
        for (int kk = 0; kk < 2; ++kk) {
            int kg = kk * 4 + lk;
            size_t rowoff = ((size_t)kg * HH + yc) * (WW * 16);
            bf16x8 a4[4], b4[4];
#pragma unroll
            for (int mt = 0; mt < 4; ++mt)
                a4[mt] = *reinterpret_cast<const bf16x8*>(
                    wsW + ((size_t)(t * 8 + kg) * 128 + wf * 64 + mt * 16 + lr) * 8);
#pragma unroll
            for (int j = 0; j < 4; ++j)
                b4[j] = *reinterpret_cast<const bf16x8*>(xb + rowoff + colb[j][dx]);
#pragma unroll
            for (int mt = 0; mt < 4; ++mt)
#pragma unroll
                for (int j = 0; j < 4; ++j)
                    acc[mt][j] = __builtin_amdgcn_mfma_f32_16x16x32_bf16(
                        a4[mt], b4[j], acc[mt][j], 0, 0, 0);
        }
    }

    // epilogue: per-wave transpose via private LDS slab; 256B nt stores
    float* le = &lds_e[w][0][0];
#pragma unroll
    for (int mt = 0; mt < 4; ++mt) {
#pragma unroll
        for (int i = 0; i < 4; ++i) {
            int f16 = lk * 4 + i;
            float bv = bl[wf * 64 + mt * 16 + f16];
#pragma unroll
            for (int j = 0; j < 4; ++j)
                le[f16 * 68 + j * 16 + lr] = acc[mt][j][i] + bv;
        }
#pragma unroll
        for (int p = 0; p < 4; ++p) {
            int f16 = p * 4 + lk;
            const float* s = &le[f16 * 68 + lr * 4];
            int f = wf * 64 + mt * 16 + f16;
            nts(out + (size_t)(n * OUTC + 256 + f) * HW + (size_t)y * WW + x0 + lr * 4,
                s[0], s[1], s[2], s[3]);
        }
    }
}

// ---------------------------------------------------------------------------
// k3: depthwise fixed filters from NC8HW8 x-tilde. Block = (n, cg, y);
// thread = pixel w: 9 coalesced 16B chunk loads (8 channels each),
// 32 coalesced scalar plane stores (nt). bf16 inputs (error << threshold).
// ---------------------------------------------------------------------------
__global__ __launch_bounds__(256) void dw_kernel(const unsigned short* __restrict__ xt,
                                                 float* __restrict__ out) {
    int b = blockIdx.x;                   // n*2048 + cg*256 + y
    int y = b & 255;
    int cg = (b >> 8) & 7;
    int n = b >> 11;
    int w = threadIdx.x;

    const unsigned short* xg = xt + (size_t)(n * 8 + cg) * HH * WW * 8;
    int yr[3], wc[3];
#pragma unroll
    for (int d = 0; d < 3; ++d) {
        yr[d] = clampi(y + d - 1, 0, HH - 1);
        wc[d] = clampi(w + d - 1, 0, WW - 1);
    }
    uint4 chunk[3][3];
#pragma unroll
    for (int r = 0; r < 3; ++r)
#pragma unroll
        for (int c = 0; c < 3; ++c)
            chunk[r][c] = *reinterpret_cast<const uint4*>(
                xg + ((size_t)yr[r] * WW + wc[c]) * 8);

    size_t ob = (size_t)n * OUTC * HW + (size_t)y * WW + w;
#pragma unroll
    for (int j = 0; j < 8; ++j) {
        float v[3][3];
#pragma unroll
        for (int r = 0; r < 3; ++r)
#pragma unroll
            for (int c = 0; c < 3; ++c) {
                unsigned word = (&chunk[r][c].x)[j >> 1];
                v[r][c] = bf2f((unsigned short)(j & 1 ? word >> 16 : word & 0xffff));
            }
        int ch = cg * 8 + j;
        float tL = v[0][0], tC = v[0][1], tR = v[0][2];
        float mL = v[1][0], mC = v[1][1], mR = v[1][2];
        float bL = v[2][0], bC = v[2][1], bR = v[2][2];
        float o0 = mC;
        float o1 = (tL + 2.f * tC + tR) - (bL + 2.f * bC + bR);
        float o2 = (tL - tR) + 2.f * (mL - mR) + (bL - bR);
        float o3 = 4.f * mC - tC - bC - mL - mR;
        __builtin_nontemporal_store(o0, out + ob + (size_t)(ch * 3 + 0) * HW);
        __builtin_nontemporal_store(o1, out + ob + (size_t)(ch * 3 + 1) * HW);
        __builtin_nontemporal_store(o2, out + ob + (size_t)(ch * 3 + 2) * HW);
        __builtin_nontemporal_store(o3, out + ob + (size_t)(192 + ch) * HW);
    }
}

extern "C" void kernel_launch(void* const* d_in, const int* in_sizes, int n_in,
                              void* d_out, int out_size, void* d_ws, size_t ws_size,
                              hipStream_t stream) {
    const float* x  = (const float*)d_in[0];
    const float* Wl = (const float*)d_in[1];
    const float* bl = (const float*)d_in[2];
    float* out = (float*)d_out;

    unsigned short* wsW = (unsigned short*)d_ws;                            // 147456 B
    unsigned short* xt  = (unsigned short*)((char*)d_ws + 262144);          // 64 MB

    wT_kernel<<<36, 256, 0, stream>>>(Wl, wsW);
    pack_kernel<<<16384, 256, 0, stream>>>(x, xt);
    learned_kernel<<<NN * 512, 256, 0, stream>>>(wsW, xt, bl, out);
    dw_kernel<<<16384, 256, 0, stream>>>(xt, out);
}

// Round 8
// 278.802 us; speedup vs baseline: 1.4953x; 1.0385x over previous
//
#include <hip/hip_runtime.h>

#define HH 256
#define WW 256
#define CC 64
#define FF 128
#define NN 8
#define OUTC 384           // 3*C sep + C lap + F learned
#define HW (HH * WW)

typedef __attribute__((ext_vector_type(8))) short bf16x8;
typedef __attribute__((ext_vector_type(4))) float f32x4;

__device__ __forceinline__ int clampi(int v, int lo, int hi) {
    return v < lo ? lo : (v > hi ? hi : v);
}

// round-to-nearest-even fp32 -> bf16
static __device__ __forceinline__ unsigned short f2bf(float x) {
    unsigned u = __builtin_bit_cast(unsigned, x);
    u += 0x7FFFu + ((u >> 16) & 1u);
    return (unsigned short)(u >> 16);
}
static __device__ __forceinline__ unsigned packbf(float a, float b) {
    return (unsigned)f2bf(a) | ((unsigned)f2bf(b) << 16);
}
static __device__ __forceinline__ float bf2f(unsigned short s) {
    return __builtin_bit_cast(float, (unsigned)s << 16);
}
static __device__ __forceinline__ void nts(float* p, float a, float b, float c, float d) {
    f32x4 v = {a, b, c, d};
    __builtin_nontemporal_store(v, reinterpret_cast<f32x4*>(p));
}

// ---------------------------------------------------------------------------
// k0: W[f][c][3][3] fp32 -> wsW bf16 [t][kg][f][8ch]  (9*8*128*8 = 147456 B)
// ---------------------------------------------------------------------------
__global__ __launch_bounds__(256) void wT_kernel(const float* __restrict__ Wl,
                                                 unsigned short* __restrict__ wsW) {
    int e = blockIdx.x * 256 + threadIdx.x;     // (t, kg, f): 9*8*128 = 9216
    if (e >= 9216) return;
    int t = e >> 10;
    int rem = e & 1023;
    int kg = rem >> 7;
    int f = rem & 127;
    unsigned u[4];
#pragma unroll
    for (int j2 = 0; j2 < 4; ++j2) {
        float a = Wl[(size_t)f * 576 + (size_t)(kg * 8 + 2 * j2) * 9 + t];
        float b = Wl[(size_t)f * 576 + (size_t)(kg * 8 + 2 * j2 + 1) * 9 + t];
        u[j2] = packbf(a, b);
    }
    *reinterpret_cast<uint4*>(wsW + (size_t)e * 8) = make_uint4(u[0], u[1], u[2], u[3]);
}

// ---------------------------------------------------------------------------
// k1: pack x NCHW fp32 -> x-tilde NC8HW8 bf16: xt[n][cg][h][w][8ch].
// ---------------------------------------------------------------------------
__global__ __launch_bounds__(256) void pack_kernel(const float* __restrict__ x,
                                                   unsigned short* __restrict__ xt) {
    int b = blockIdx.x;                   // n*2048 + cg*256 + y
    int y = b & 255;
    int cg = (b >> 8) & 7;
    int n = b >> 11;
    int w = threadIdx.x;
    const float* xp = x + ((size_t)(n * CC + cg * 8)) * HW + (size_t)y * WW + w;
    unsigned u[4];
#pragma unroll
    for (int j2 = 0; j2 < 4; ++j2)
        u[j2] = packbf(xp[(size_t)(2 * j2) * HW], xp[(size_t)(2 * j2 + 1) * HW]);
    *reinterpret_cast<uint4*>(xt + ((size_t)((n * 8 + cg) * HH + y) * WW + w) * 8) =
        make_uint4(u[0], u[1], u[2], u[3]);
}

// ---------------------------------------------------------------------------
// k2: learned conv, zero staging / zero barriers. Block = 4 waves =
// 128 f x 128 px x 1 row; wave = 64 f x 64 px, acc[4][4].
// T1 XCD-chunked swizzle: XCD k owns image n=k; y advances sequentially so
// the 3-row x-tilde window stays L2-hot (18x tap re-reads -> local L2 hits).
// ---------------------------------------------------------------------------
__global__ __launch_bounds__(256, 4) void learned_kernel(const unsigned short* __restrict__ wsW,
                                                         const unsigned short* __restrict__ xt,
                                                         const float* __restrict__ bl,
                                                         float* __restrict__ out) {
    __shared__ float lds_e[4][16][68];        // 17408 B, per-wave slabs

    int bid = blockIdx.x;
    int q = ((bid & 7) << 9) | (bid >> 3);    // bijective: 4096 = 8 * 512
    int xs = q & 1;
    int y = (q >> 1) & 255;
    int n = q >> 9;

    int tid = threadIdx.x;
    int lane = tid & 63;
    int w = tid >> 6;
    int wf = w >> 1;                          // f-half (0..1)
    int ws = w & 1;                           // px 64-segment (0..1)
    int x0 = xs * 128 + ws * 64;
    int lr = lane & 15;
    int lk = lane >> 4;

    const char* xb = reinterpret_cast<const char*>(xt) + (size_t)n * (8 * HH * WW * 16);

    int colb[4][3];
#pragma unroll
    for (int j = 0; j < 4; ++j)
#pragma unroll
        for (int dx = 0; dx < 3; ++dx)
            colb[j][dx] = clampi(x0 + j * 16 + lr + dx - 1, 0, WW - 1) * 16;

    f32x4 acc[4][4] = {};                     // [mt (16f tile)][j (16px group)]

#pragma unroll
    for (int t = 0; t < 9; ++t) {
        int dy = t / 3, dx = t - 3 * (t / 3);
        int yc = clampi(y + dy - 1, 0, HH - 1);
#pragma unroll
        for (int kk = 0; kk < 2; ++kk) {
            int kg = kk * 4 + lk;
            size_t rowoff = ((size_t)kg * HH + yc) * (WW * 16);
            bf16x8 a4[4], b4[4];
#pragma unroll
            for (int mt = 0; mt < 4; ++mt)
                a4[mt] = *reinterpret_cast<const bf16x8*>(
                    wsW + ((size_t)(t * 8 + kg) * 128 + wf * 64 + mt * 16 + lr) * 8);
#pragma unroll
            for (int j = 0; j < 4; ++j)
                b4[j] = *reinterpret_cast<const bf16x8*>(xb + rowoff + colb[j][dx]);
#pragma unroll
            for (int mt = 0; mt < 4; ++mt)
#pragma unroll
                for (int j = 0; j < 4; ++j)
                    acc[mt][j] = __builtin_amdgcn_mfma_f32_16x16x32_bf16(
                        a4[mt], b4[j], acc[mt][j], 0, 0, 0);
        }
    }

    // epilogue: per-wave transpose via private LDS slab; 256B nt stores
    float* le = &lds_e[w][0][0];
#pragma unroll
    for (int mt = 0; mt < 4; ++mt) {
#pragma unroll
        for (int i = 0; i < 4; ++i) {
            int f16 = lk * 4 + i;
            float bv = bl[wf * 64 + mt * 16 + f16];
#pragma unroll
            for (int j = 0; j < 4; ++j)
                le[f16 * 68 + j * 16 + lr] = acc[mt][j][i] + bv;
        }
#pragma unroll
        for (int p = 0; p < 4; ++p) {
            int f16 = p * 4 + lk;
            const float* s = &le[f16 * 68 + lr * 4];
            int f = wf * 64 + mt * 16 + f16;
            nts(out + (size_t)(n * OUTC + 256 + f) * HW + (size_t)y * WW + x0 + lr * 4,
                s[0], s[1], s[2], s[3]);
        }
    }
}

// ---------------------------------------------------------------------------
// k3: depthwise fixed filters from NC8HW8 x-tilde, T1-swizzled like k2.
// ---------------------------------------------------------------------------
__global__ __launch_bounds__(256) void dw_kernel(const unsigned short* __restrict__ xt,
                                                 float* __restrict__ out) {
    int bid = blockIdx.x;
    int b = ((bid & 7) << 11) | (bid >> 3);   // bijective: 16384 = 8 * 2048
    int y = b & 255;
    int cg = (b >> 8) & 7;
    int n = b >> 11;
    int w = threadIdx.x;

    const unsigned short* xg = xt + (size_t)(n * 8 + cg) * HH * WW * 8;
    int yr[3], wc[3];
#pragma unroll
    for (int d = 0; d < 3; ++d) {
        yr[d] = clampi(y + d - 1, 0, HH - 1);
        wc[d] = clampi(w + d - 1, 0, WW - 1);
    }
    uint4 chunk[3][3];
#pragma unroll
    for (int r = 0; r < 3; ++r)
#pragma unroll
        for (int c = 0; c < 3; ++c)
            chunk[r][c] = *reinterpret_cast<const uint4*>(
                xg + ((size_t)yr[r] * WW + wc[c]) * 8);

    size_t ob = (size_t)n * OUTC * HW + (size_t)y * WW + w;
#pragma unroll
    for (int j = 0; j < 8; ++j) {
        float v[3][3];
#pragma unroll
        for (int r = 0; r < 3; ++r)
#pragma unroll
            for (int c = 0; c < 3; ++c) {
                unsigned word = (&chunk[r][c].x)[j >> 1];
                v[r][c] = bf2f((unsigned short)(j & 1 ? word >> 16 : word & 0xffff));
            }
        int ch = cg * 8 + j;
        float tL = v[0][0], tC = v[0][1], tR = v[0][2];
        float mL = v[1][0], mC = v[1][1], mR = v[1][2];
        float bL = v[2][0], bC = v[2][1], bR = v[2][2];
        float o0 = mC;
        float o1 = (tL + 2.f * tC + tR) - (bL + 2.f * bC + bR);
        float o2 = (tL - tR) + 2.f * (mL - mR) + (bL - bR);
        float o3 = 4.f * mC - tC - bC - mL - mR;
        __builtin_nontemporal_store(o0, out + ob + (size_t)(ch * 3 + 0) * HW);
        __builtin_nontemporal_store(o1, out + ob + (size_t)(ch * 3 + 1) * HW);
        __builtin_nontemporal_store(o2, out + ob + (size_t)(ch * 3 + 2) * HW);
        __builtin_nontemporal_store(o3, out + ob + (size_t)(192 + ch) * HW);
    }
}

extern "C" void kernel_launch(void* const* d_in, const int* in_sizes, int n_in,
                              void* d_out, int out_size, void* d_ws, size_t ws_size,
                              hipStream_t stream) {
    const float* x  = (const float*)d_in[0];
    const float* Wl = (const float*)d_in[1];
    const float* bl = (const float*)d_in[2];
    float* out = (float*)d_out;

    unsigned short* wsW = (unsigned short*)d_ws;                            // 147456 B
    unsigned short* xt  = (unsigned short*)((char*)d_ws + 262144);          // 64 MB

    wT_kernel<<<36, 256, 0, stream>>>(Wl, wsW);
    pack_kernel<<<16384, 256, 0, stream>>>(x, xt);
    learned_kernel<<<NN * 512, 256, 0, stream>>>(wsW, xt, bl, out);
    dw_kernel<<<16384, 256, 0, stream>>>(xt, out);
}

// Round 9
// 255.940 us; speedup vs baseline: 1.6289x; 1.0893x over previous
//
#include <hip/hip_runtime.h>

#define HH 256
#define WW 256
#define CC 64
#define FF 128
#define NN 8
#define OUTC 384           // 3*C sep + C lap + F learned
#define HW (HH * WW)

typedef __attribute__((ext_vector_type(8))) short bf16x8;
typedef __attribute__((ext_vector_type(4))) float f32x4;

__device__ __forceinline__ int clampi(int v, int lo, int hi) {
    return v < lo ? lo : (v > hi ? hi : v);
}

// round-to-nearest-even fp32 -> bf16
static __device__ __forceinline__ unsigned short f2bf(float x) {
    unsigned u = __builtin_bit_cast(unsigned, x);
    u += 0x7FFFu + ((u >> 16) & 1u);
    return (unsigned short)(u >> 16);
}
static __device__ __forceinline__ unsigned packbf(float a, float b) {
    return (unsigned)f2bf(a) | ((unsigned)f2bf(b) << 16);
}
static __device__ __forceinline__ float bf2f(unsigned short s) {
    return __builtin_bit_cast(float, (unsigned)s << 16);
}
static __device__ __forceinline__ void nts(float* p, float a, float b, float c, float d) {
    f32x4 v = {a, b, c, d};
    __builtin_nontemporal_store(v, reinterpret_cast<f32x4*>(p));
}

// ---------------------------------------------------------------------------
// k0: W[f][c][3][3] fp32 -> wsW bf16 [t][kg][f][8ch]  (9*8*128*8 = 147456 B)
// ---------------------------------------------------------------------------
__global__ __launch_bounds__(256) void wT_kernel(const float* __restrict__ Wl,
                                                 unsigned short* __restrict__ wsW) {
    int e = blockIdx.x * 256 + threadIdx.x;     // (t, kg, f): 9*8*128 = 9216
    if (e >= 9216) return;
    int t = e >> 10;
    int rem = e & 1023;
    int kg = rem >> 7;
    int f = rem & 127;
    unsigned u[4];
#pragma unroll
    for (int j2 = 0; j2 < 4; ++j2) {
        float a = Wl[(size_t)f * 576 + (size_t)(kg * 8 + 2 * j2) * 9 + t];
        float b = Wl[(size_t)f * 576 + (size_t)(kg * 8 + 2 * j2 + 1) * 9 + t];
        u[j2] = packbf(a, b);
    }
    *reinterpret_cast<uint4*>(wsW + (size_t)e * 8) = make_uint4(u[0], u[1], u[2], u[3]);
}

// ---------------------------------------------------------------------------
// k1: pack x NCHW fp32 -> x-tilde NC8HW8 bf16: xt[n][cg][h][w][8ch].
// ---------------------------------------------------------------------------
__global__ __launch_bounds__(256) void pack_kernel(const float* __restrict__ x,
                                                   unsigned short* __restrict__ xt) {
    int b = blockIdx.x;                   // n*2048 + cg*256 + y
    int y = b & 255;
    int cg = (b >> 8) & 7;
    int n = b >> 11;
    int w = threadIdx.x;
    const float* xp = x + ((size_t)(n * CC + cg * 8)) * HW + (size_t)y * WW + w;
    unsigned u[4];
#pragma unroll
    for (int j2 = 0; j2 < 4; ++j2)
        u[j2] = packbf(xp[(size_t)(2 * j2) * HW], xp[(size_t)(2 * j2 + 1) * HW]);
    *reinterpret_cast<uint4*>(xt + ((size_t)((n * 8 + cg) * HH + y) * WW + w) * 8) =
        make_uint4(u[0], u[1], u[2], u[3]);
}

// ---------------------------------------------------------------------------
// k2: FUSED learned conv (bf16 MFMA, zero staging/barriers) + depthwise
// fixed filters. Block = 4 waves = (n, y, xs half-row of 128 px).
// Learned: wave (wf, ws) = 64f x 64px, acc[4][4]; b-frags direct 16B loads
// from NC8HW8 x-tilde (256B/quarter-wave segments, L1/L2-hot).
// dw: after tap t<8, chunk cg=t: wave (wf,ws) computes channels wf*4..+3,
// px ws*64..+63 from the same cache-hot x-tilde lines; 256B/wave nt stores
// drain under the MFMA pipeline. T1 XCD-chunked swizzle keeps the 3-row
// window L2-local.
// ---------------------------------------------------------------------------
__global__ __launch_bounds__(256, 4) void fused_kernel(const unsigned short* __restrict__ wsW,
                                                       const unsigned short* __restrict__ xt,
                                                       const float* __restrict__ bl,
                                                       float* __restrict__ out) {
    __shared__ float lds_e[4][16][68];        // 17408 B, per-wave slabs

    int bid = blockIdx.x;
    int q = ((bid & 7) << 9) | (bid >> 3);    // bijective: 4096 = 8 * 512
    int xs = q & 1;
    int y = (q >> 1) & 255;
    int n = q >> 9;

    int tid = threadIdx.x;
    int lane = tid & 63;
    int w = tid >> 6;
    int wf = w >> 1;                          // f-half (0..1)
    int ws = w & 1;                           // px 64-segment (0..1)
    int x0 = xs * 128 + ws * 64;
    int lr = lane & 15;
    int lk = lane >> 4;

    const char* xb = reinterpret_cast<const char*>(xt) + (size_t)n * (8 * HH * WW * 16);

    int colb[4][3];
#pragma unroll
    for (int j = 0; j < 4; ++j)
#pragma unroll
        for (int dx = 0; dx < 3; ++dx)
            colb[j][dx] = clampi(x0 + j * 16 + lr + dx - 1, 0, WW - 1) * 16;

    // dw per-thread geometry: px = x0 + lane (wave covers 64 px, 256B stores)
    int pxg = x0 + lane;
    int dwyr[3], dwwc[3];
#pragma unroll
    for (int d = 0; d < 3; ++d) {
        dwyr[d] = clampi(y + d - 1, 0, HH - 1);
        dwwc[d] = clampi(pxg + d - 1, 0, WW - 1);
    }

    f32x4 acc[4][4] = {};                     // [mt (16f tile)][j (16px group)]

#pragma unroll
    for (int t = 0; t < 9; ++t) {
        int dy = t / 3, dx = t - 3 * (t / 3);
        int yc = clampi(y + dy - 1, 0, HH - 1);
#pragma unroll
        for (int kk = 0; kk < 2; ++kk) {
            int kg = kk * 4 + lk;
            size_t rowoff = ((size_t)kg * HH + yc) * (WW * 16);
            bf16x8 a4[4], b4[4];
#pragma unroll
            for (int mt = 0; mt < 4; ++mt)
                a4[mt] = *reinterpret_cast<const bf16x8*>(
                    wsW + ((size_t)(t * 8 + kg) * 128 + wf * 64 + mt * 16 + lr) * 8);
#pragma unroll
            for (int j = 0; j < 4; ++j)
                b4[j] = *reinterpret_cast<const bf16x8*>(xb + rowoff + colb[j][dx]);
#pragma unroll
            for (int mt = 0; mt < 4; ++mt)
#pragma unroll
                for (int j = 0; j < 4; ++j)
                    acc[mt][j] = __builtin_amdgcn_mfma_f32_16x16x32_bf16(
                        a4[mt], b4[j], acc[mt][j], 0, 0, 0);
        }

        // ---- dw chunk t: cg = t; 4 channels (wf*4..+3) x 64 px per wave
        if (t < 8) {
            int cg = t;
            const char* cgbase = xb + (size_t)cg * HH * (WW * 16) + wf * 8;
            uint2 c9[3][3];
#pragma unroll
            for (int r = 0; r < 3; ++r)
#pragma unroll
                for (int d = 0; d < 3; ++d)
                    c9[r][d] = *reinterpret_cast<const uint2*>(
                        cgbase + ((size_t)dwyr[r] * WW + dwwc[d]) * 16);
            size_t ob = (size_t)n * OUTC * HW + (size_t)y * WW + pxg;
#pragma unroll
            for (int i = 0; i < 4; ++i) {
                float v[3][3];
#pragma unroll
                for (int r = 0; r < 3; ++r)
#pragma unroll
                    for (int d = 0; d < 3; ++d) {
                        unsigned word = (i < 2) ? c9[r][d].x : c9[r][d].y;
                        v[r][d] = bf2f((unsigned short)((i & 1) ? (word >> 16) : (word & 0xffff)));
                    }
                int ch = cg * 8 + wf * 4 + i;
                float o0 = v[1][1];
                float o1 = (v[0][0] + 2.f * v[0][1] + v[0][2]) - (v[2][0] + 2.f * v[2][1] + v[2][2]);
                float o2 = (v[0][0] - v[0][2]) + 2.f * (v[1][0] - v[1][2]) + (v[2][0] - v[2][2]);
                float o3 = 4.f * v[1][1] - v[0][1] - v[2][1] - v[1][0] - v[1][2];
                __builtin_nontemporal_store(o0, out + ob + (size_t)(ch * 3 + 0) * HW);
                __builtin_nontemporal_store(o1, out + ob + (size_t)(ch * 3 + 1) * HW);
                __builtin_nontemporal_store(o2, out + ob + (size_t)(ch * 3 + 2) * HW);
                __builtin_nontemporal_store(o3, out + ob + (size_t)(192 + ch) * HW);
            }
        }
    }

    // epilogue: per-wave transpose via private LDS slab; 256B nt stores
    float* le = &lds_e[w][0][0];
#pragma unroll
    for (int mt = 0; mt < 4; ++mt) {
#pragma unroll
        for (int i = 0; i < 4; ++i) {
            int f16 = lk * 4 + i;
            float bv = bl[wf * 64 + mt * 16 + f16];
#pragma unroll
            for (int j = 0; j < 4; ++j)
                le[f16 * 68 + j * 16 + lr] = acc[mt][j][i] + bv;
        }
#pragma unroll
        for (int p = 0; p < 4; ++p) {
            int f16 = p * 4 + lk;
            const float* s = &le[f16 * 68 + lr * 4];
            int f = wf * 64 + mt * 16 + f16;
            nts(out + (size_t)(n * OUTC + 256 + f) * HW + (size_t)y * WW + x0 + lr * 4,
                s[0], s[1], s[2], s[3]);
        }
    }
}

extern "C" void kernel_launch(void* const* d_in, const int* in_sizes, int n_in,
                              void* d_out, int out_size, void* d_ws, size_t ws_size,
                              hipStream_t stream) {
    const float* x  = (const float*)d_in[0];
    const float* Wl = (const float*)d_in[1];
    const float* bl = (const float*)d_in[2];
    float* out = (float*)d_out;

    unsigned short* wsW = (unsigned short*)d_ws;                            // 147456 B
    unsigned short* xt  = (unsigned short*)((char*)d_ws + 262144);          // 64 MB

    wT_kernel<<<36, 256, 0, stream>>>(Wl, wsW);
    pack_kernel<<<16384, 256, 0, stream>>>(x, xt);
    fused_kernel<<<NN * 512, 256, 0, stream>>>(wsW, xt, bl, out);
}